// Round 2
// baseline (473.145 us; speedup 1.0000x reference)
//
#include <hip/hip_runtime.h>
#include <math.h>

#define BB 16
#define CC 512
#define HWN 4096
#define INNER 256
#define EPSV 1e-5f

__device__ __forceinline__ float wave_sum(float s) {
    for (int off = 32; off; off >>= 1) s += __shfl_down(s, off);
    return s;
}
__device__ __forceinline__ float block_sum(float v, volatile float* s_red) {
    for (int off = 32; off; off >>= 1) v += __shfl_down(v, off);
    __syncthreads();
    if ((threadIdx.x & 63) == 0) s_red[threadIdx.x >> 6] = v;
    __syncthreads();
    return s_red[0] + s_red[1] + s_red[2] + s_red[3];
}
__device__ __forceinline__ float block_max(float v, volatile float* s_red) {
    for (int off = 32; off; off >>= 1) v = fmaxf(v, __shfl_down(v, off));
    __syncthreads();
    if ((threadIdx.x & 63) == 0) s_red[threadIdx.x >> 6] = v;
    __syncthreads();
    return fmaxf(fmaxf(s_red[0], s_red[1]), fmaxf(s_red[2], s_red[3]));
}
__device__ __forceinline__ float fsigmoid(float v) {
    return __builtin_amdgcn_rcpf(1.f + __expf(-v));
}

// pass 1: cm_logits[b,hw] += x.Wcq (8 c-blocks collide); xsum[b,c] += sum_hw x
// wave-per-channel: wave w owns channels c0+w+4i, 4 coalesced float4 loads/lane.
__global__ __launch_bounds__(256) void k1_pass(
    const float* __restrict__ x, const float* __restrict__ wcq,
    float* __restrict__ cm_logits, float* __restrict__ xsum)
{
    const int t = threadIdx.x, lane = t & 63, w = t >> 6;
    const int hw0 = blockIdx.x * 1024;
    const int c0  = blockIdx.y * 64;
    const int b   = blockIdx.z;
    __shared__ float s_w[64];
    __shared__ float s_red[4][1024];
    if (t < 64) s_w[t] = wcq[c0 + t];
    __syncthreads();

    const float* xb = x + ((size_t)b * CC + c0) * HWN + hw0 + lane * 4;
    float4 cm0 = {0,0,0,0}, cm1 = cm0, cm2 = cm0, cm3 = cm0;
    #pragma unroll 4
    for (int ci = 0; ci < 16; ++ci) {
        const int cl = w + ci * 4;
        const float* p = xb + (size_t)cl * HWN;
        float4 v0 = *(const float4*)(p);
        float4 v1 = *(const float4*)(p + 256);
        float4 v2 = *(const float4*)(p + 512);
        float4 v3 = *(const float4*)(p + 768);
        const float wc = s_w[cl];
        cm0.x = fmaf(v0.x, wc, cm0.x); cm0.y = fmaf(v0.y, wc, cm0.y);
        cm0.z = fmaf(v0.z, wc, cm0.z); cm0.w = fmaf(v0.w, wc, cm0.w);
        cm1.x = fmaf(v1.x, wc, cm1.x); cm1.y = fmaf(v1.y, wc, cm1.y);
        cm1.z = fmaf(v1.z, wc, cm1.z); cm1.w = fmaf(v1.w, wc, cm1.w);
        cm2.x = fmaf(v2.x, wc, cm2.x); cm2.y = fmaf(v2.y, wc, cm2.y);
        cm2.z = fmaf(v2.z, wc, cm2.z); cm2.w = fmaf(v2.w, wc, cm2.w);
        cm3.x = fmaf(v3.x, wc, cm3.x); cm3.y = fmaf(v3.y, wc, cm3.y);
        cm3.z = fmaf(v3.z, wc, cm3.z); cm3.w = fmaf(v3.w, wc, cm3.w);
        float s = (((v0.x+v0.y)+(v0.z+v0.w)) + ((v1.x+v1.y)+(v1.z+v1.w)))
                + (((v2.x+v2.y)+(v2.z+v2.w)) + ((v3.x+v3.y)+(v3.z+v3.w)));
        s = wave_sum(s);
        if (lane == 0) atomicAdd(&xsum[b * CC + c0 + cl], s);
    }
    *(float4*)&s_red[w][      lane*4] = cm0;
    *(float4*)&s_red[w][256 + lane*4] = cm1;
    *(float4*)&s_red[w][512 + lane*4] = cm2;
    *(float4*)&s_red[w][768 + lane*4] = cm3;
    __syncthreads();
    float4 r0 = *(float4*)&s_red[0][t*4];
    float4 r1 = *(float4*)&s_red[1][t*4];
    float4 r2 = *(float4*)&s_red[2][t*4];
    float4 r3 = *(float4*)&s_red[3][t*4];
    float* cp = cm_logits + b * HWN + hw0 + t * 4;
    atomicAdd(cp + 0, (r0.x + r1.x) + (r2.x + r3.x));
    atomicAdd(cp + 1, (r0.y + r1.y) + (r2.y + r3.y));
    atomicAdd(cp + 2, (r0.z + r1.z) + (r2.z + r3.z));
    atomicAdd(cp + 3, (r0.w + r1.w) + (r2.w + r3.w));
}

// small: softmax(cm_logits)->cm_sm ; avg=softmax(Wsq@xsum/HW) ; wsv_eff=avg^T Wsv
__global__ __launch_bounds__(256) void k2_small(
    const float* __restrict__ Wsq, const float* __restrict__ Wsv,
    const float* __restrict__ cm_logits, const float* __restrict__ xsum,
    float* __restrict__ cm_sm, float* __restrict__ wsv_eff)
{
    const int b = blockIdx.x, t = threadIdx.x, lane = t & 63, w = t >> 6;
    __shared__ float s_red[4];
    __shared__ float s_xsum[CC];
    __shared__ float s_avg[INNER];

    s_xsum[t]       = xsum[b * CC + t];
    s_xsum[t + 256] = xsum[b * CC + t + 256];

    // (a) softmax over HW
    const float* cl = cm_logits + b * HWN;
    float* co = cm_sm + b * HWN;
    float lmax = -1e30f;
    for (int i = t; i < HWN; i += 256) lmax = fmaxf(lmax, cl[i]);
    lmax = block_max(lmax, s_red);
    float lsum = 0.f;
    for (int i = t; i < HWN; i += 256) {
        float e = __expf(cl[i] - lmax);
        co[i] = e;
        lsum += e;
    }
    lsum = block_sum(lsum, s_red);
    float rinv = __builtin_amdgcn_rcpf(lsum);
    for (int i = t; i < HWN; i += 256) co[i] *= rinv;
    __syncthreads();

    // (b) avg_raw[k] = Wsq[k,:] . xsum / HW  — per-wave coalesced dot
    for (int i = 0; i < 64; ++i) {
        const int k = w * 64 + i;
        const float* row = Wsq + (size_t)k * CC + lane * 4;
        float4 q0 = *(const float4*)(row);
        float4 q1 = *(const float4*)(row + 256);
        float4 x0 = *(const float4*)&s_xsum[lane * 4];
        float4 x1 = *(const float4*)&s_xsum[256 + lane * 4];
        float s = fmaf(q0.x,x0.x, fmaf(q0.y,x0.y, fmaf(q0.z,x0.z, q0.w*x0.w)))
                + fmaf(q1.x,x1.x, fmaf(q1.y,x1.y, fmaf(q1.z,x1.z, q1.w*x1.w)));
        s = wave_sum(s);
        if (lane == 0) s_avg[k] = s * (1.0f / HWN);
    }
    __syncthreads();
    // softmax over 256 (t == k)
    float a = s_avg[t];
    float m2 = block_max(a, s_red);
    float e = __expf(a - m2);
    float s2 = block_sum(e, s_red);
    s_avg[t] = e * __builtin_amdgcn_rcpf(s2);
    __syncthreads();

    // (c) wsv_eff[b,c] = sum_k avg[k]*Wsv[k,c]  (c = t, t+256: coalesced)
    float a0 = 0.f, a1 = 0.f;
    for (int k = 0; k < INNER; ++k) {
        float av = s_avg[k];
        a0 = fmaf(av, Wsv[(size_t)k * CC + t], a0);
        a1 = fmaf(av, Wsv[(size_t)k * CC + t + 256], a1);
    }
    wsv_eff[b * CC + t]       = a0;
    wsv_eff[b * CC + t + 256] = a1;
}

// pass 2: ctx[b,hw] += x.wsv_eff ; xw[b,c] += sum_hw x*cm_sm
__global__ __launch_bounds__(256) void k3_pass(
    const float* __restrict__ x, const float* __restrict__ wsv_eff,
    const float* __restrict__ cm_sm, float* __restrict__ ctx, float* __restrict__ xw)
{
    const int t = threadIdx.x, lane = t & 63, w = t >> 6;
    const int hw0 = blockIdx.x * 1024;
    const int c0  = blockIdx.y * 64;
    const int b   = blockIdx.z;
    __shared__ float s_w[64];
    __shared__ float s_red[4][1024];
    if (t < 64) s_w[t] = wsv_eff[b * CC + c0 + t];
    __syncthreads();

    const float* mb = cm_sm + b * HWN + hw0 + lane * 4;
    float4 m0 = *(const float4*)(mb);
    float4 m1 = *(const float4*)(mb + 256);
    float4 m2 = *(const float4*)(mb + 512);
    float4 m3 = *(const float4*)(mb + 768);

    const float* xb = x + ((size_t)b * CC + c0) * HWN + hw0 + lane * 4;
    float4 a0 = {0,0,0,0}, a1 = a0, a2 = a0, a3 = a0;
    #pragma unroll 4
    for (int ci = 0; ci < 16; ++ci) {
        const int cl = w + ci * 4;
        const float* p = xb + (size_t)cl * HWN;
        float4 v0 = *(const float4*)(p);
        float4 v1 = *(const float4*)(p + 256);
        float4 v2 = *(const float4*)(p + 512);
        float4 v3 = *(const float4*)(p + 768);
        const float wc = s_w[cl];
        a0.x = fmaf(v0.x, wc, a0.x); a0.y = fmaf(v0.y, wc, a0.y);
        a0.z = fmaf(v0.z, wc, a0.z); a0.w = fmaf(v0.w, wc, a0.w);
        a1.x = fmaf(v1.x, wc, a1.x); a1.y = fmaf(v1.y, wc, a1.y);
        a1.z = fmaf(v1.z, wc, a1.z); a1.w = fmaf(v1.w, wc, a1.w);
        a2.x = fmaf(v2.x, wc, a2.x); a2.y = fmaf(v2.y, wc, a2.y);
        a2.z = fmaf(v2.z, wc, a2.z); a2.w = fmaf(v2.w, wc, a2.w);
        a3.x = fmaf(v3.x, wc, a3.x); a3.y = fmaf(v3.y, wc, a3.y);
        a3.z = fmaf(v3.z, wc, a3.z); a3.w = fmaf(v3.w, wc, a3.w);
        float s = fmaf(v0.x,m0.x, fmaf(v0.y,m0.y, fmaf(v0.z,m0.z, v0.w*m0.w)))
                + fmaf(v1.x,m1.x, fmaf(v1.y,m1.y, fmaf(v1.z,m1.z, v1.w*m1.w)))
                + fmaf(v2.x,m2.x, fmaf(v2.y,m2.y, fmaf(v2.z,m2.z, v2.w*m2.w)))
                + fmaf(v3.x,m3.x, fmaf(v3.y,m3.y, fmaf(v3.z,m3.z, v3.w*m3.w)));
        s = wave_sum(s);
        if (lane == 0) atomicAdd(&xw[b * CC + c0 + cl], s);
    }
    *(float4*)&s_red[w][      lane*4] = a0;
    *(float4*)&s_red[w][256 + lane*4] = a1;
    *(float4*)&s_red[w][512 + lane*4] = a2;
    *(float4*)&s_red[w][768 + lane*4] = a3;
    __syncthreads();
    float4 r0 = *(float4*)&s_red[0][t*4];
    float4 r1 = *(float4*)&s_red[1][t*4];
    float4 r2 = *(float4*)&s_red[2][t*4];
    float4 r3 = *(float4*)&s_red[3][t*4];
    float* cp = ctx + b * HWN + hw0 + t * 4;
    atomicAdd(cp + 0, (r0.x + r1.x) + (r2.x + r3.x));
    atomicAdd(cp + 1, (r0.y + r1.y) + (r2.y + r3.y));
    atomicAdd(cp + 2, (r0.z + r1.z) + (r2.z + r3.z));
    atomicAdd(cp + 3, (r0.w + r1.w) + (r2.w + r3.w));
}

// small: context = Wcv@xw ; z = Wcz@context ; LayerNorm ; mask = sigmoid(z)
__global__ __launch_bounds__(256) void k4_small(
    const float* __restrict__ Wcv, const float* __restrict__ Wcz,
    const float* __restrict__ gamma, const float* __restrict__ beta,
    const float* __restrict__ xw, float* __restrict__ mask)
{
    const int b = blockIdx.x, t = threadIdx.x, lane = t & 63, w = t >> 6;
    __shared__ float s_red[4];
    __shared__ float s_xw[CC];
    __shared__ float s_ctx[INNER];
    __shared__ float s_z[CC];
    s_xw[t]       = xw[b * CC + t];
    s_xw[t + 256] = xw[b * CC + t + 256];
    __syncthreads();

    // context[k] — per-wave coalesced dot over 512
    for (int i = 0; i < 64; ++i) {
        const int k = w * 64 + i;
        const float* row = Wcv + (size_t)k * CC + lane * 4;
        float4 q0 = *(const float4*)(row);
        float4 q1 = *(const float4*)(row + 256);
        float4 x0 = *(const float4*)&s_xw[lane * 4];
        float4 x1 = *(const float4*)&s_xw[256 + lane * 4];
        float s = fmaf(q0.x,x0.x, fmaf(q0.y,x0.y, fmaf(q0.z,x0.z, q0.w*x0.w)))
                + fmaf(q1.x,x1.x, fmaf(q1.y,x1.y, fmaf(q1.z,x1.z, q1.w*x1.w)));
        s = wave_sum(s);
        if (lane == 0) s_ctx[k] = s;
    }
    __syncthreads();

    // z[o] — per-wave coalesced dot over 256 (one float4/lane covers all k)
    for (int i = 0; i < 128; ++i) {
        const int o = w * 128 + i;
        float4 q = *(const float4*)(Wcz + (size_t)o * INNER + lane * 4);
        float4 c = *(const float4*)&s_ctx[lane * 4];
        float s = fmaf(q.x,c.x, fmaf(q.y,c.y, fmaf(q.z,c.z, q.w*c.w)));
        s = wave_sum(s);
        if (lane == 0) s_z[o] = s;
    }
    __syncthreads();

    float z0 = s_z[t], z1 = s_z[t + 256];
    float mu = block_sum(z0 + z1, s_red) * (1.f / CC);
    float d0 = z0 - mu, d1 = z1 - mu;
    float var = block_sum(d0 * d0 + d1 * d1, s_red) * (1.f / CC);
    float rstd = rsqrtf(var + EPSV);
    float zn0 = fmaf(d0 * rstd, gamma[t], beta[t]);
    float zn1 = fmaf(d1 * rstd, gamma[t + 256], beta[t + 256]);
    mask[b * CC + t]       = fsigmoid(zn0);
    mask[b * CC + t + 256] = fsigmoid(zn1);
}

// final: out = x * (mask[b,c] + sigmoid(ctx[b,hw]))
__global__ __launch_bounds__(256) void k5_final(
    const float* __restrict__ x, const float* __restrict__ ctx,
    const float* __restrict__ mask, float* __restrict__ out)
{
    const int t  = threadIdx.x;
    const int hw = blockIdx.x * 1024 + 4 * t;
    const int c  = blockIdx.y;
    const int b  = blockIdx.z;
    const float m = mask[b * CC + c];
    float4 cv = *(const float4*)(ctx + b * HWN + hw);
    float4 s;
    s.x = fsigmoid(cv.x);
    s.y = fsigmoid(cv.y);
    s.z = fsigmoid(cv.z);
    s.w = fsigmoid(cv.w);
    const size_t base = ((size_t)b * CC + c) * HWN + hw;
    float4 xv = *(const float4*)(x + base);
    float4 o;
    o.x = xv.x * (m + s.x);
    o.y = xv.y * (m + s.y);
    o.z = xv.z * (m + s.z);
    o.w = xv.w * (m + s.w);
    *(float4*)(out + base) = o;
}

extern "C" void kernel_launch(void* const* d_in, const int* in_sizes, int n_in,
                              void* d_out, int out_size, void* d_ws, size_t ws_size,
                              hipStream_t stream) {
    const float* x     = (const float*)d_in[0];
    const float* Wsq   = (const float*)d_in[1];
    const float* Wsv   = (const float*)d_in[2];
    const float* Wcq   = (const float*)d_in[3];
    const float* Wcv   = (const float*)d_in[4];
    const float* Wcz   = (const float*)d_in[5];
    const float* gamma = (const float*)d_in[6];
    const float* beta  = (const float*)d_in[7];
    float* out = (float*)d_out;
    float* ws  = (float*)d_ws;

    float* cm_logits = ws;             // 65536  (atomic -> zeroed)
    float* ctx       = ws + 65536;     // 65536  (atomic -> zeroed)
    float* xsum      = ws + 131072;    // 8192   (atomic -> zeroed)
    float* xw        = ws + 139264;    // 8192   (atomic -> zeroed)
    float* cm_sm     = ws + 147456;    // 65536
    float* wsv_eff   = ws + 212992;    // 8192
    float* mask      = ws + 221184;    // 8192

    hipMemsetAsync(d_ws, 0, 147456 * sizeof(float), stream);

    k1_pass<<<dim3(4, 8, BB), 256, 0, stream>>>(x, Wcq, cm_logits, xsum);
    k2_small<<<BB, 256, 0, stream>>>(Wsq, Wsv, cm_logits, xsum, cm_sm, wsv_eff);
    k3_pass<<<dim3(4, 8, BB), 256, 0, stream>>>(x, wsv_eff, cm_sm, ctx, xw);
    k4_small<<<BB, 256, 0, stream>>>(Wcv, Wcz, gamma, beta, xw, mask);
    k5_final<<<dim3(4, CC, BB), 256, 0, stream>>>(x, ctx, mask, out);
}

// Round 3
// 360.484 us; speedup vs baseline: 1.3125x; 1.3125x over previous
//
#include <hip/hip_runtime.h>
#include <math.h>

#define BB 16
#define CC 512
#define HWN 4096
#define INNER 256
#define EPSV 1e-5f

__device__ __forceinline__ float wave_sum(float s) {
    for (int off = 32; off; off >>= 1) s += __shfl_down(s, off);
    return s;
}
__device__ __forceinline__ float block_sum(float v, volatile float* s_red) {
    for (int off = 32; off; off >>= 1) v += __shfl_down(v, off);
    __syncthreads();
    if ((threadIdx.x & 63) == 0) s_red[threadIdx.x >> 6] = v;
    __syncthreads();
    return s_red[0] + s_red[1] + s_red[2] + s_red[3];
}
__device__ __forceinline__ float block_max(float v, volatile float* s_red) {
    for (int off = 32; off; off >>= 1) v = fmaxf(v, __shfl_down(v, off));
    __syncthreads();
    if ((threadIdx.x & 63) == 0) s_red[threadIdx.x >> 6] = v;
    __syncthreads();
    return fmaxf(fmaxf(s_red[0], s_red[1]), fmaxf(s_red[2], s_red[3]));
}
__device__ __forceinline__ float fsigmoid(float v) {
    return __builtin_amdgcn_rcpf(1.f + __expf(-v));
}

// ---- pass 1: cm_logits[b,hw] += x.Wcq ; xsum[b,c] += sum_hw x ---------------
__global__ __launch_bounds__(256) void k1_pass(
    const float* __restrict__ x, const float* __restrict__ wcq,
    float* __restrict__ cm_logits, float* __restrict__ xsum)
{
    const int t = threadIdx.x, lane = t & 63, w = t >> 6;
    const int hw0 = blockIdx.x * 1024;
    const int c0  = blockIdx.y * 64;
    const int b   = blockIdx.z;
    __shared__ float s_w[64];
    __shared__ float s_red[4][1024];
    if (t < 64) s_w[t] = wcq[c0 + t];
    __syncthreads();

    const float* xb = x + ((size_t)b * CC + c0) * HWN + hw0 + lane * 4;
    float4 cm0 = {0,0,0,0}, cm1 = cm0, cm2 = cm0, cm3 = cm0;
    #pragma unroll 4
    for (int ci = 0; ci < 16; ++ci) {
        const int cl = w + ci * 4;
        const float* p = xb + (size_t)cl * HWN;
        float4 v0 = *(const float4*)(p);
        float4 v1 = *(const float4*)(p + 256);
        float4 v2 = *(const float4*)(p + 512);
        float4 v3 = *(const float4*)(p + 768);
        const float wc = s_w[cl];
        cm0.x = fmaf(v0.x, wc, cm0.x); cm0.y = fmaf(v0.y, wc, cm0.y);
        cm0.z = fmaf(v0.z, wc, cm0.z); cm0.w = fmaf(v0.w, wc, cm0.w);
        cm1.x = fmaf(v1.x, wc, cm1.x); cm1.y = fmaf(v1.y, wc, cm1.y);
        cm1.z = fmaf(v1.z, wc, cm1.z); cm1.w = fmaf(v1.w, wc, cm1.w);
        cm2.x = fmaf(v2.x, wc, cm2.x); cm2.y = fmaf(v2.y, wc, cm2.y);
        cm2.z = fmaf(v2.z, wc, cm2.z); cm2.w = fmaf(v2.w, wc, cm2.w);
        cm3.x = fmaf(v3.x, wc, cm3.x); cm3.y = fmaf(v3.y, wc, cm3.y);
        cm3.z = fmaf(v3.z, wc, cm3.z); cm3.w = fmaf(v3.w, wc, cm3.w);
        float s = (((v0.x+v0.y)+(v0.z+v0.w)) + ((v1.x+v1.y)+(v1.z+v1.w)))
                + (((v2.x+v2.y)+(v2.z+v2.w)) + ((v3.x+v3.y)+(v3.z+v3.w)));
        s = wave_sum(s);
        if (lane == 0) atomicAdd(&xsum[b * CC + c0 + cl], s);
    }
    *(float4*)&s_red[w][      lane*4] = cm0;
    *(float4*)&s_red[w][256 + lane*4] = cm1;
    *(float4*)&s_red[w][512 + lane*4] = cm2;
    *(float4*)&s_red[w][768 + lane*4] = cm3;
    __syncthreads();
    float4 r0 = *(float4*)&s_red[0][t*4];
    float4 r1 = *(float4*)&s_red[1][t*4];
    float4 r2 = *(float4*)&s_red[2][t*4];
    float4 r3 = *(float4*)&s_red[3][t*4];
    float* cp = cm_logits + b * HWN + hw0 + t * 4;
    atomicAdd(cp + 0, (r0.x + r1.x) + (r2.x + r3.x));
    atomicAdd(cp + 1, (r0.y + r1.y) + (r2.y + r3.y));
    atomicAdd(cp + 2, (r0.z + r1.z) + (r2.z + r3.z));
    atomicAdd(cp + 3, (r0.w + r1.w) + (r2.w + r3.w));
}

// ---- cm softmax stats: cmstats[b] = {max, 1/sum_exp} ------------------------
__global__ __launch_bounds__(256) void k2a_cmstats(
    const float* __restrict__ cm_logits, float* __restrict__ cmstats)
{
    const int b = blockIdx.x, t = threadIdx.x;
    __shared__ float s_red[4];
    const float* cl = cm_logits + b * HWN;
    float lmax = -1e30f;
    #pragma unroll 4
    for (int i = t; i < HWN; i += 256) lmax = fmaxf(lmax, cl[i]);
    lmax = block_max(lmax, s_red);
    float lsum = 0.f;
    #pragma unroll 4
    for (int i = t; i < HWN; i += 256) lsum += __expf(cl[i] - lmax);
    lsum = block_sum(lsum, s_red);
    if (t == 0) {
        cmstats[2 * b]     = lmax;
        cmstats[2 * b + 1] = __builtin_amdgcn_rcpf(lsum);
    }
}

// ---- y[b,k] = scale * W[k,:512] . v[b,:512]  (grid: BB x 4 k-tiles) ---------
__global__ __launch_bounds__(256) void k_mv512(
    const float* __restrict__ W, const float* __restrict__ v,
    float* __restrict__ y, float scale)
{
    const int b = blockIdx.x, t = threadIdx.x, lane = t & 63, w = t >> 6;
    const int k0 = blockIdx.y * 64;
    __shared__ float s_v[CC];
    s_v[t]       = v[b * CC + t];
    s_v[t + 256] = v[b * CC + t + 256];
    __syncthreads();
    float4 x0 = *(const float4*)&s_v[lane * 4];
    float4 x1 = *(const float4*)&s_v[256 + lane * 4];
    #pragma unroll 8
    for (int i = 0; i < 16; ++i) {
        const int k = k0 + w * 16 + i;
        const float* row = W + (size_t)k * CC + lane * 4;
        float4 q0 = *(const float4*)(row);
        float4 q1 = *(const float4*)(row + 256);
        float s = fmaf(q0.x,x0.x, fmaf(q0.y,x0.y, fmaf(q0.z,x0.z, q0.w*x0.w)))
                + fmaf(q1.x,x1.x, fmaf(q1.y,x1.y, fmaf(q1.z,x1.z, q1.w*x1.w)));
        s = wave_sum(s);
        if (lane == 0) y[b * INNER + k] = s * scale;
    }
}

// ---- softmax(avg_logits) ; wsv_eff[b,c] = sum_k avg_sm[k]*Wsv[k,c] ----------
__global__ __launch_bounds__(256) void k2c_wsv(
    const float* __restrict__ Wsv, const float* __restrict__ avg_logits,
    float* __restrict__ wsv_eff)
{
    const int b = blockIdx.x, t = threadIdx.x;
    const int c = blockIdx.y * 256 + t;
    __shared__ float s_red[4];
    __shared__ float s_avg[INNER];
    float a = avg_logits[b * INNER + t];
    float m = block_max(a, s_red);
    float e = __expf(a - m);
    float s2 = block_sum(e, s_red);
    s_avg[t] = e * __builtin_amdgcn_rcpf(s2);
    __syncthreads();
    float acc = 0.f;
    #pragma unroll 8
    for (int k = 0; k < INNER; ++k)
        acc = fmaf(s_avg[k], Wsv[(size_t)k * CC + c], acc);
    wsv_eff[b * CC + c] = acc;
}

// ---- pass 2: ctx[b,hw] += x.wsv_eff ; xw[b,c] += sum_hw x*softmax(cm) -------
__global__ __launch_bounds__(256) void k3_pass(
    const float* __restrict__ x, const float* __restrict__ wsv_eff,
    const float* __restrict__ cm_logits, const float* __restrict__ cmstats,
    float* __restrict__ ctx, float* __restrict__ xw)
{
    const int t = threadIdx.x, lane = t & 63, w = t >> 6;
    const int hw0 = blockIdx.x * 1024;
    const int c0  = blockIdx.y * 64;
    const int b   = blockIdx.z;
    __shared__ float s_w[64];
    __shared__ float s_red[4][1024];
    if (t < 64) s_w[t] = wsv_eff[b * CC + c0 + t];
    __syncthreads();

    const float cmax = cmstats[2 * b], crinv = cmstats[2 * b + 1];
    const float* mb = cm_logits + b * HWN + hw0 + lane * 4;
    float4 m0 = *(const float4*)(mb);
    float4 m1 = *(const float4*)(mb + 256);
    float4 m2 = *(const float4*)(mb + 512);
    float4 m3 = *(const float4*)(mb + 768);
    m0.x = __expf(m0.x - cmax) * crinv; m0.y = __expf(m0.y - cmax) * crinv;
    m0.z = __expf(m0.z - cmax) * crinv; m0.w = __expf(m0.w - cmax) * crinv;
    m1.x = __expf(m1.x - cmax) * crinv; m1.y = __expf(m1.y - cmax) * crinv;
    m1.z = __expf(m1.z - cmax) * crinv; m1.w = __expf(m1.w - cmax) * crinv;
    m2.x = __expf(m2.x - cmax) * crinv; m2.y = __expf(m2.y - cmax) * crinv;
    m2.z = __expf(m2.z - cmax) * crinv; m2.w = __expf(m2.w - cmax) * crinv;
    m3.x = __expf(m3.x - cmax) * crinv; m3.y = __expf(m3.y - cmax) * crinv;
    m3.z = __expf(m3.z - cmax) * crinv; m3.w = __expf(m3.w - cmax) * crinv;

    const float* xb = x + ((size_t)b * CC + c0) * HWN + hw0 + lane * 4;
    float4 a0 = {0,0,0,0}, a1 = a0, a2 = a0, a3 = a0;
    #pragma unroll 4
    for (int ci = 0; ci < 16; ++ci) {
        const int cl = w + ci * 4;
        const float* p = xb + (size_t)cl * HWN;
        float4 v0 = *(const float4*)(p);
        float4 v1 = *(const float4*)(p + 256);
        float4 v2 = *(const float4*)(p + 512);
        float4 v3 = *(const float4*)(p + 768);
        const float wc = s_w[cl];
        a0.x = fmaf(v0.x, wc, a0.x); a0.y = fmaf(v0.y, wc, a0.y);
        a0.z = fmaf(v0.z, wc, a0.z); a0.w = fmaf(v0.w, wc, a0.w);
        a1.x = fmaf(v1.x, wc, a1.x); a1.y = fmaf(v1.y, wc, a1.y);
        a1.z = fmaf(v1.z, wc, a1.z); a1.w = fmaf(v1.w, wc, a1.w);
        a2.x = fmaf(v2.x, wc, a2.x); a2.y = fmaf(v2.y, wc, a2.y);
        a2.z = fmaf(v2.z, wc, a2.z); a2.w = fmaf(v2.w, wc, a2.w);
        a3.x = fmaf(v3.x, wc, a3.x); a3.y = fmaf(v3.y, wc, a3.y);
        a3.z = fmaf(v3.z, wc, a3.z); a3.w = fmaf(v3.w, wc, a3.w);
        float s = fmaf(v0.x,m0.x, fmaf(v0.y,m0.y, fmaf(v0.z,m0.z, v0.w*m0.w)))
                + fmaf(v1.x,m1.x, fmaf(v1.y,m1.y, fmaf(v1.z,m1.z, v1.w*m1.w)))
                + fmaf(v2.x,m2.x, fmaf(v2.y,m2.y, fmaf(v2.z,m2.z, v2.w*m2.w)))
                + fmaf(v3.x,m3.x, fmaf(v3.y,m3.y, fmaf(v3.z,m3.z, v3.w*m3.w)));
        s = wave_sum(s);
        if (lane == 0) atomicAdd(&xw[b * CC + c0 + cl], s);
    }
    *(float4*)&s_red[w][      lane*4] = a0;
    *(float4*)&s_red[w][256 + lane*4] = a1;
    *(float4*)&s_red[w][512 + lane*4] = a2;
    *(float4*)&s_red[w][768 + lane*4] = a3;
    __syncthreads();
    float4 r0 = *(float4*)&s_red[0][t*4];
    float4 r1 = *(float4*)&s_red[1][t*4];
    float4 r2 = *(float4*)&s_red[2][t*4];
    float4 r3 = *(float4*)&s_red[3][t*4];
    float* cp = ctx + b * HWN + hw0 + t * 4;
    atomicAdd(cp + 0, (r0.x + r1.x) + (r2.x + r3.x));
    atomicAdd(cp + 1, (r0.y + r1.y) + (r2.y + r3.y));
    atomicAdd(cp + 2, (r0.z + r1.z) + (r2.z + r3.z));
    atomicAdd(cp + 3, (r0.w + r1.w) + (r2.w + r3.w));
}

// ---- z[b,o] = Wcz[o,:256] . context[b,:]  (grid: BB x 4 o-tiles) ------------
__global__ __launch_bounds__(256) void k4b_z(
    const float* __restrict__ Wcz, const float* __restrict__ context,
    float* __restrict__ zbuf)
{
    const int b = blockIdx.x, t = threadIdx.x, lane = t & 63, w = t >> 6;
    const int o0 = blockIdx.y * 128;
    __shared__ float s_c[INNER];
    s_c[t] = context[b * INNER + t];
    __syncthreads();
    float4 cv = *(const float4*)&s_c[lane * 4];
    #pragma unroll 8
    for (int i = 0; i < 32; ++i) {
        const int o = o0 + w * 32 + i;
        float4 q = *(const float4*)(Wcz + (size_t)o * INNER + lane * 4);
        float s = fmaf(q.x,cv.x, fmaf(q.y,cv.y, fmaf(q.z,cv.z, q.w*cv.w)));
        s = wave_sum(s);
        if (lane == 0) zbuf[b * CC + o] = s;
    }
}

// ---- LayerNorm(z)->sigmoid mask ; ctx_sig = sigmoid(ctx) --------------------
__global__ __launch_bounds__(256) void k4c_ln(
    const float* __restrict__ gamma, const float* __restrict__ beta,
    const float* __restrict__ zbuf, const float* __restrict__ ctx,
    float* __restrict__ mask, float* __restrict__ ctx_sig)
{
    const int b = blockIdx.x, t = threadIdx.x;
    __shared__ float s_red[4];
    float z0 = zbuf[b * CC + t], z1 = zbuf[b * CC + t + 256];
    float mu = block_sum(z0 + z1, s_red) * (1.f / CC);
    float d0 = z0 - mu, d1 = z1 - mu;
    float var = block_sum(d0 * d0 + d1 * d1, s_red) * (1.f / CC);
    float rstd = rsqrtf(var + EPSV);
    float zn0 = fmaf(d0 * rstd, gamma[t], beta[t]);
    float zn1 = fmaf(d1 * rstd, gamma[t + 256], beta[t + 256]);
    mask[b * CC + t]       = fsigmoid(zn0);
    mask[b * CC + t + 256] = fsigmoid(zn1);
    const float* ci = ctx + b * HWN;
    float* cs = ctx_sig + b * HWN;
    #pragma unroll 4
    for (int i = t; i < HWN; i += 256) cs[i] = fsigmoid(ci[i]);
}

// ---- final: out = x * (mask[b,c] + ctx_sig[b,hw]) ---------------------------
__global__ __launch_bounds__(256) void k5_final(
    const float* __restrict__ x, const float* __restrict__ ctx_sig,
    const float* __restrict__ mask, float* __restrict__ out)
{
    const int t  = threadIdx.x;
    const int hw = blockIdx.x * 1024 + 4 * t;
    const int c  = blockIdx.y;
    const int b  = blockIdx.z;
    const float m = mask[b * CC + c];
    float4 s = *(const float4*)(ctx_sig + b * HWN + hw);
    const size_t base = ((size_t)b * CC + c) * HWN + hw;
    float4 xv = *(const float4*)(x + base);
    float4 o;
    o.x = xv.x * (m + s.x);
    o.y = xv.y * (m + s.y);
    o.z = xv.z * (m + s.z);
    o.w = xv.w * (m + s.w);
    *(float4*)(out + base) = o;
}

extern "C" void kernel_launch(void* const* d_in, const int* in_sizes, int n_in,
                              void* d_out, int out_size, void* d_ws, size_t ws_size,
                              hipStream_t stream) {
    const float* x     = (const float*)d_in[0];
    const float* Wsq   = (const float*)d_in[1];
    const float* Wsv   = (const float*)d_in[2];
    const float* Wcq   = (const float*)d_in[3];
    const float* Wcv   = (const float*)d_in[4];
    const float* Wcz   = (const float*)d_in[5];
    const float* gamma = (const float*)d_in[6];
    const float* beta  = (const float*)d_in[7];
    float* out = (float*)d_out;
    float* ws  = (float*)d_ws;

    float* cm_logits  = ws;             // 65536  (atomic -> zeroed)
    float* ctx        = ws + 65536;     // 65536  (atomic -> zeroed)
    float* xsum       = ws + 131072;    // 8192   (atomic -> zeroed)
    float* xw         = ws + 139264;    // 8192   (atomic -> zeroed)
    float* avg_logits = ws + 147456;    // 4096
    float* wsv_eff    = ws + 151552;    // 8192
    float* maskbuf    = ws + 159744;    // 8192
    float* zbuf       = ws + 167936;    // 8192
    float* context    = ws + 176128;    // 4096
    float* ctx_sig    = ws + 180224;    // 65536
    float* cmstats    = ws + 245760;    // 32

    hipMemsetAsync(d_ws, 0, 147456 * sizeof(float), stream);

    k1_pass<<<dim3(4, 8, BB), 256, 0, stream>>>(x, Wcq, cm_logits, xsum);
    k2a_cmstats<<<BB, 256, 0, stream>>>(cm_logits, cmstats);
    k_mv512<<<dim3(BB, 4), 256, 0, stream>>>(Wsq, xsum, avg_logits, 1.0f / HWN);
    k2c_wsv<<<dim3(BB, 2), 256, 0, stream>>>(Wsv, avg_logits, wsv_eff);
    k3_pass<<<dim3(4, 8, BB), 256, 0, stream>>>(x, wsv_eff, cm_logits, cmstats, ctx, xw);
    k_mv512<<<dim3(BB, 4), 256, 0, stream>>>(Wcv, xw, context, 1.0f);
    k4b_z<<<dim3(BB, 4), 256, 0, stream>>>(Wcz, context, zbuf);
    k4c_ln<<<BB, 256, 0, stream>>>(gamma, beta, zbuf, ctx, maskbuf, ctx_sig);
    k5_final<<<dim3(4, CC, BB), 256, 0, stream>>>(x, ctx_sig, maskbuf, out);
}